// Round 1
// baseline (6473.634 us; speedup 1.0000x reference)
//
#include <hip/hip_runtime.h>
#include <math.h>

#define N_   1024
#define K_   8
#define OTL  3
#define SKL  3
#define GWBL 2
#define INVB 10.0f      /* 1/PROX_BETA */
#define EPSV 1e-16f
#define NN   ((size_t)N_ * N_)

/* ---------------- elementwise kernels ---------------- */

__global__ void sigmoid_k(const float* __restrict__ x, float* __restrict__ y, size_t n4) {
    size_t i = blockIdx.x * (size_t)blockDim.x + threadIdx.x;
    size_t st = (size_t)gridDim.x * blockDim.x;
    for (; i < n4; i += st) {
        float4 v = ((const float4*)x)[i];
        v.x = 1.f / (1.f + expf(-v.x));
        v.y = 1.f / (1.f + expf(-v.y));
        v.z = 1.f / (1.f + expf(-v.z));
        v.w = 1.f / (1.f + expf(-v.w));
        ((float4*)y)[i] = v;
    }
}

// T[k][r][c] = ps[k*N+r] * pb[c]
__global__ void initT_k(float* __restrict__ T, const float* __restrict__ ps,
                        const float* __restrict__ pb, int nb) {
    size_t total = (size_t)nb * NN / 4;
    size_t st = (size_t)gridDim.x * blockDim.x;
    for (size_t i4 = blockIdx.x * (size_t)blockDim.x + threadIdx.x; i4 < total; i4 += st) {
        size_t idx = i4 * 4;
        int k = (int)(idx >> 20);
        int r = (int)((idx >> 10) & (N_ - 1));
        int c = (int)(idx & (N_ - 1));
        float av = ps[k * N_ + r];
        float4 pv = *(const float4*)(pb + c);
        float4 o;
        o.x = av * pv.x; o.y = av * pv.y; o.z = av * pv.z; o.w = av * pv.w;
        *(float4*)(T + idx) = o;
    }
}

// T[k][r][c] *= a[k*N+r] * b[k*N+c]
__global__ void tupd_k(float* __restrict__ T, const float* __restrict__ a,
                       const float* __restrict__ b, int nb) {
    size_t total = (size_t)nb * NN / 4;
    size_t st = (size_t)gridDim.x * blockDim.x;
    for (size_t i4 = blockIdx.x * (size_t)blockDim.x + threadIdx.x; i4 < total; i4 += st) {
        size_t idx = i4 * 4;
        int k = (int)(idx >> 20);
        int r = (int)((idx >> 10) & (N_ - 1));
        int c = (int)(idx & (N_ - 1));
        float av = a[k * N_ + r];
        float4 bv = *(const float4*)(b + k * N_ + c);
        float4 t = *(float4*)(T + idx);
        t.x *= av * bv.x; t.y *= av * bv.y; t.z *= av * bv.z; t.w *= av * bv.w;
        *(float4*)(T + idx) = t;
    }
}

__global__ void copy_k(float* __restrict__ dst, const float* __restrict__ src, size_t n) {
    size_t i = blockIdx.x * (size_t)blockDim.x + threadIdx.x;
    size_t st = (size_t)gridDim.x * blockDim.x;
    for (; i < n; i += st) dst[i] = src[i];
}

__global__ void zero_k(float* p) {
    if (threadIdx.x == 0 && blockIdx.x == 0) p[0] = 0.f;
}

/* ---------------- row/col reductions ---------------- */

// y[b*N+row] = sum_c A[b][row][c]^2 * p[c(+bN)]   (wave per row)
__global__ void sq_matvec_k(const float* __restrict__ A, const float* __restrict__ p,
                            float* __restrict__ y, int batched_p) {
    int b = blockIdx.y;
    int wave = threadIdx.x >> 6, lane = threadIdx.x & 63;
    int row = blockIdx.x * 4 + wave;
    const float* Ar = A + (size_t)b * NN + (size_t)row * N_;
    const float* pp = p + (batched_p ? b * N_ : 0);
    float s = 0.f;
    for (int c = lane * 4; c < N_; c += 256) {
        float4 av = *(const float4*)(Ar + c);
        float4 pv = *(const float4*)(pp + c);
        s += av.x * av.x * pv.x + av.y * av.y * pv.y + av.z * av.z * pv.z + av.w * av.w * pv.w;
    }
    #pragma unroll
    for (int off = 32; off; off >>= 1) s += __shfl_down(s, off);
    if (lane == 0) y[b * N_ + row] = s;
}

// b[bat*N+c] = pb[c] / (sum_i K[bat][i][c]*a[bat*N+i] + eps)
__global__ void sink_col_k(const float* __restrict__ Km, const float* __restrict__ a,
                           const float* __restrict__ pb, float* __restrict__ b) {
    int bat = blockIdx.y;
    const float* Kb = Km + (size_t)bat * NN;
    const float* ab = a + bat * N_;
    int c = blockIdx.x * 64 + (threadIdx.x & 63);
    int rg = threadIdx.x >> 6;
    float s = 0.f;
    for (int i = rg * 256; i < rg * 256 + 256; ++i)
        s += Kb[(size_t)i * N_ + c] * ab[i];
    __shared__ float red[4][64];
    red[rg][threadIdx.x & 63] = s;
    __syncthreads();
    if (rg == 0) {
        int lc = threadIdx.x;
        s = red[0][lc] + red[1][lc] + red[2][lc] + red[3][lc];
        b[bat * N_ + c] = pb[c] / (s + EPSV);
    }
}

// a[bat*N+row] = ps[row(+batN)] / (sum_c K[bat][row][c]*b[bat*N+c] + eps)
__global__ void sink_row_k(const float* __restrict__ Km, const float* __restrict__ bvec,
                           const float* __restrict__ ps, float* __restrict__ a, int batched_ps) {
    int bat = blockIdx.y;
    int wave = threadIdx.x >> 6, lane = threadIdx.x & 63;
    int row = blockIdx.x * 4 + wave;
    const float* Kr = Km + (size_t)bat * NN + (size_t)row * N_;
    const float* bb = bvec + bat * N_;
    float s = 0.f;
    for (int c = lane * 4; c < N_; c += 256) {
        float4 kv = *(const float4*)(Kr + c);
        float4 bv = *(const float4*)(bb + c);
        s += kv.x * bv.x + kv.y * bv.y + kv.z * bv.z + kv.w * bv.w;
    }
    #pragma unroll
    for (int off = 32; off; off >>= 1) s += __shfl_down(s, off);
    if (lane == 0) {
        float psv = ps[(batched_ps ? bat * N_ : 0) + row];
        a[bat * N_ + row] = psv / (s + EPSV);
    }
}

/* ---------------- GEMM (fp32, 128x128x16, 8x8/thread) ----------------
   Logical: C = op(A) @ op(B), 1024^3.
   TRA: A_log[m][k] = A_phys[k][m];  TRB: B_log[k][n] = B_phys[n][k]
   RED: sum over batches with weight wts[k] (applied on A-tile); C single.
   EPI: 0 plain store | 1 store acc/(pvec[r]*pvec[c])
        2 in-place prox: C[idx] = exp(-(rv[z*N+r]+cv[c]-2*acc)*INVB) * C[idx]
        3 no store: atomicAdd(dout, sum (rv[r]+cv[c]-2*acc)*C[idx])              */
template<int TRA, int TRB, int RED, int EPI>
__global__ __launch_bounds__(256)
void gemm_k(const float* __restrict__ A, const float* __restrict__ B, float* __restrict__ C,
            size_t sA, size_t sB, int nbatch,
            const float* __restrict__ wts,
            const float* __restrict__ rv, const float* __restrict__ cv,
            const float* __restrict__ pvec, float* __restrict__ dout) {
    __shared__ float As[16][132];
    __shared__ float Bs[16][132];
    const int bm = blockIdx.x * 128;
    const int bn = blockIdx.y * 128;
    const int tid = threadIdx.x;
    const int tx = tid & 15, ty = tid >> 4;

    float acc[8][8];
    #pragma unroll
    for (int i = 0; i < 8; i++)
        #pragma unroll
        for (int j = 0; j < 8; j++) acc[i][j] = 0.f;

    const int nbat = RED ? nbatch : 1;
    for (int kb = 0; kb < nbat; ++kb) {
        const int bz = RED ? kb : blockIdx.z;
        const float* Ab = A + (size_t)bz * sA;
        const float* Bb = B + (size_t)bz * sB;
        const float w = RED ? wts[bz] : 1.0f;

        for (int k0 = 0; k0 < N_; k0 += 16) {
            if (TRA == 0) {
                const int row = tid >> 2;
                const int c4 = (tid & 3) << 2;
                #pragma unroll
                for (int rr = 0; rr < 128; rr += 64) {
                    float4 v = *(const float4*)(Ab + (size_t)(bm + row + rr) * N_ + k0 + c4);
                    As[c4 + 0][row + rr] = v.x;
                    As[c4 + 1][row + rr] = v.y;
                    As[c4 + 2][row + rr] = v.z;
                    As[c4 + 3][row + rr] = v.w;
                }
            } else {
                const int row = tid >> 5;
                const int c4 = (tid & 31) << 2;
                #pragma unroll
                for (int rr = 0; rr < 16; rr += 8) {
                    float4 v = *(const float4*)(Ab + (size_t)(k0 + row + rr) * N_ + bm + c4);
                    if (RED) { v.x *= w; v.y *= w; v.z *= w; v.w *= w; }
                    *(float4*)&As[row + rr][c4] = v;
                }
            }
            if (TRB == 0) {
                const int row = tid >> 5;
                const int c4 = (tid & 31) << 2;
                #pragma unroll
                for (int rr = 0; rr < 16; rr += 8) {
                    float4 v = *(const float4*)(Bb + (size_t)(k0 + row + rr) * N_ + bn + c4);
                    *(float4*)&Bs[row + rr][c4] = v;
                }
            } else {
                const int nl = tid >> 2;
                const int k4 = (tid & 3) << 2;
                #pragma unroll
                for (int rr = 0; rr < 128; rr += 64) {
                    float4 v = *(const float4*)(Bb + (size_t)(bn + nl + rr) * N_ + k0 + k4);
                    Bs[k4 + 0][nl + rr] = v.x;
                    Bs[k4 + 1][nl + rr] = v.y;
                    Bs[k4 + 2][nl + rr] = v.z;
                    Bs[k4 + 3][nl + rr] = v.w;
                }
            }
            __syncthreads();
            #pragma unroll
            for (int kk = 0; kk < 16; ++kk) {
                float a[8], b[8];
                *(float4*)&a[0] = *(const float4*)&As[kk][ty * 8];
                *(float4*)&a[4] = *(const float4*)&As[kk][ty * 8 + 4];
                *(float4*)&b[0] = *(const float4*)&Bs[kk][tx * 8];
                *(float4*)&b[4] = *(const float4*)&Bs[kk][tx * 8 + 4];
                #pragma unroll
                for (int i = 0; i < 8; i++)
                    #pragma unroll
                    for (int j = 0; j < 8; j++)
                        acc[i][j] = fmaf(a[i], b[j], acc[i][j]);
            }
            __syncthreads();
        }
    }

    float* Cb = C + (RED ? (size_t)0 : (size_t)blockIdx.z * NN);
    const int r0 = bm + ty * 8, c0 = bn + tx * 8;

    if (EPI == 3) {
        float s = 0.f;
        #pragma unroll
        for (int i = 0; i < 8; i++) {
            const int r = r0 + i;
            const float rvi = rv[r];
            #pragma unroll
            for (int j = 0; j < 8; j++) {
                const int c = c0 + j;
                s += (rvi + cv[c] - 2.f * acc[i][j]) * Cb[(size_t)r * N_ + c];
            }
        }
        #pragma unroll
        for (int off = 32; off; off >>= 1) s += __shfl_down(s, off);
        __shared__ float wr[4];
        if ((tid & 63) == 0) wr[tid >> 6] = s;
        __syncthreads();
        if (tid == 0) atomicAdd(dout, wr[0] + wr[1] + wr[2] + wr[3]);
        return;
    }

    #pragma unroll
    for (int i = 0; i < 8; i++) {
        const int r = r0 + i;
        float rvi = 0.f, pr = 0.f;
        if (EPI == 2) rvi = rv[blockIdx.z * N_ + r];
        if (EPI == 1) pr = pvec[r];
        #pragma unroll
        for (int j = 0; j < 8; j += 4) {
            const int c = c0 + j;
            float4 v;
            v.x = acc[i][j]; v.y = acc[i][j + 1]; v.z = acc[i][j + 2]; v.w = acc[i][j + 3];
            if (EPI == 1) {
                const float4 pc = *(const float4*)(pvec + c);
                v.x /= pr * pc.x; v.y /= pr * pc.y; v.z /= pr * pc.z; v.w /= pr * pc.w;
            }
            if (EPI == 2) {
                const float4 cvv = *(const float4*)(cv + c);
                const float4 t = *(const float4*)(Cb + (size_t)r * N_ + c);
                v.x = expf(-(rvi + cvv.x - 2.f * v.x) * INVB) * t.x;
                v.y = expf(-(rvi + cvv.y - 2.f * v.y) * INVB) * t.y;
                v.z = expf(-(rvi + cvv.z - 2.f * v.z) * INVB) * t.z;
                v.w = expf(-(rvi + cvv.w - 2.f * v.w) * INVB) * t.w;
            }
            *(float4*)(Cb + (size_t)r * N_ + c) = v;
        }
    }
}

/* ---------------- host sequence ---------------- */

extern "C" void kernel_launch(void* const* d_in, const int* in_sizes, int n_in,
                              void* d_out, int out_size, void* d_ws, size_t ws_size,
                              hipStream_t stream) {
    const float* Gm    = (const float*)d_in[0];   // (N,N)
    const float* pm    = (const float*)d_in[1];   // (N,1)
    const float* atoms = (const float*)d_in[2];   // (K,N,N)
    const float* probs = (const float*)d_in[3];   // (K,N,1)
    const float* wts   = (const float*)d_in[4];   // (K,)
    float* out = (float*)d_out;                   // [0]=d_fgw, [1..]=G_bary

    float* ws    = (float*)d_ws;
    float* Gk    = ws;                       // K*N*N
    float* T     = Gk + (size_t)K_ * NN;     // K*N*N
    float* M     = T  + (size_t)K_ * NN;     // K*N*N
    float* Gb    = M  + (size_t)K_ * NN;     // N*N
    float* Gk2ps = Gb + NN;                  // K*N
    float* Gm2pm = Gk2ps + K_ * N_;          // N
    float* Gb2pb = Gm2pm + N_;               // N
    float* avec  = Gb2pb + N_;               // K*N
    float* bvec  = avec + K_ * N_;           // K*N

    const dim3 blk(256);
    const dim3 gemm_grid_b(8, 8, K_);
    const dim3 gemm_grid_1(8, 8, 1);

    // setup
    sigmoid_k<<<2048, blk, 0, stream>>>(atoms, Gk, (size_t)K_ * NN / 4);
    sq_matvec_k<<<dim3(N_ / 4, K_), blk, 0, stream>>>(Gk, probs, Gk2ps, 1);
    sq_matvec_k<<<dim3(N_ / 4, 1), blk, 0, stream>>>(Gm, pm, Gm2pm, 0);
    hipMemcpyAsync(Gb, Gm, NN * sizeof(float), hipMemcpyDeviceToDevice, stream);

    for (int it = 0; it < GWBL; ++it) {
        sq_matvec_k<<<dim3(N_ / 4, 1), blk, 0, stream>>>(Gb, pm, Gb2pb, 0);
        initT_k<<<2048, blk, 0, stream>>>(T, probs, pm, K_);
        for (int ot = 0; ot < OTL; ++ot) {
            // M = Gk @ T
            gemm_k<0,0,0,0><<<gemm_grid_b, blk, 0, stream>>>(Gk, T, M, NN, NN, K_,
                nullptr, nullptr, nullptr, nullptr, nullptr);
            // T = exp(-(cost_st - 2 M Gb^T)/beta) * T   (in place)
            gemm_k<0,1,0,2><<<gemm_grid_b, blk, 0, stream>>>(M, Gb, T, NN, 0, K_,
                nullptr, Gk2ps, Gb2pb, nullptr, nullptr);
            // Sinkhorn
            hipMemcpyAsync(avec, probs, (size_t)K_ * N_ * sizeof(float),
                           hipMemcpyDeviceToDevice, stream);
            for (int s = 0; s < SKL; ++s) {
                sink_col_k<<<dim3(N_ / 64, K_), blk, 0, stream>>>(T, avec, pm, bvec);
                sink_row_k<<<dim3(N_ / 4, K_), blk, 0, stream>>>(T, bvec, probs, avec, 1);
            }
            tupd_k<<<2048, blk, 0, stream>>>(T, avec, bvec, K_);
        }
        // GT = Gk @ T   (into M)
        gemm_k<0,0,0,0><<<gemm_grid_b, blk, 0, stream>>>(Gk, T, M, NN, NN, K_,
            nullptr, nullptr, nullptr, nullptr, nullptr);
        // Gb = sum_k w_k T_k^T GT_k / (pm pm^T)
        gemm_k<1,0,1,1><<<gemm_grid_1, blk, 0, stream>>>(T, M, Gb, NN, NN, K_,
            wts, nullptr, nullptr, pm, nullptr);
    }

    // final fgwd(Gm, pm, Gb, pm)
    sq_matvec_k<<<dim3(N_ / 4, 1), blk, 0, stream>>>(Gb, pm, Gb2pb, 0);
    initT_k<<<2048, blk, 0, stream>>>(T, pm, pm, 1);
    for (int ot = 0; ot < OTL; ++ot) {
        gemm_k<0,0,0,0><<<gemm_grid_1, blk, 0, stream>>>(Gm, T, M, NN, NN, 1,
            nullptr, nullptr, nullptr, nullptr, nullptr);
        gemm_k<0,1,0,2><<<gemm_grid_1, blk, 0, stream>>>(M, Gb, T, NN, 0, 1,
            nullptr, Gm2pm, Gb2pb, nullptr, nullptr);
        hipMemcpyAsync(avec, pm, (size_t)N_ * sizeof(float),
                       hipMemcpyDeviceToDevice, stream);
        for (int s = 0; s < SKL; ++s) {
            sink_col_k<<<dim3(N_ / 64, 1), blk, 0, stream>>>(T, avec, pm, bvec);
            sink_row_k<<<dim3(N_ / 4, 1), blk, 0, stream>>>(T, bvec, pm, avec, 0);
        }
        tupd_k<<<2048, blk, 0, stream>>>(T, avec, bvec, 1);
    }
    // d = sum( (cost_st - 2 Gm T Gb^T) * T )
    gemm_k<0,0,0,0><<<gemm_grid_1, blk, 0, stream>>>(Gm, T, M, NN, NN, 1,
        nullptr, nullptr, nullptr, nullptr, nullptr);
    zero_k<<<1, 1, 0, stream>>>(out);
    gemm_k<0,1,0,3><<<gemm_grid_1, blk, 0, stream>>>(M, Gb, T, NN, 0, 1,
        nullptr, Gm2pm, Gb2pb, nullptr, out);
    copy_k<<<1024, blk, 0, stream>>>(out + 1, Gb, NN);
}

// Round 2
// 1264.518 us; speedup vs baseline: 5.1194x; 5.1194x over previous
//
#include <hip/hip_runtime.h>
#include <math.h>

#define N_   1024
#define K_   8
#define OTL  3
#define SKL  3
#define GWBL 2
#define INVB 10.0f      /* 1/PROX_BETA */
#define EPSV 1e-16f
#define NN   ((size_t)N_ * N_)

typedef __attribute__((ext_vector_type(8))) short short8;
typedef __attribute__((ext_vector_type(4))) float f32x4;
typedef unsigned short bfu;

__device__ __forceinline__ float b2f(bfu u) {
    unsigned x = ((unsigned)u) << 16;
    return __builtin_bit_cast(float, x);
}
__device__ __forceinline__ bfu f2b(float f) {
    unsigned u = __builtin_bit_cast(unsigned, f);
    unsigned r = u + 0x7fffu + ((u >> 16) & 1u);   // RTN-even (finite values only)
    return (bfu)(r >> 16);
}

/* ============ bf16 MFMA GEMM: C[m][n] = sum_k A[m][k]*B[n][k] ============
   A,B bf16 row-major (K-contiguous), 1024x1024 per batch slice.
   128x128 tile, 256 thr = 4 waves (2x2), 64x64 per wave, mfma 16x16x32.
   EPI 0: store C bf16 (Cz = C + z*sC)
   EPI 1: store C fp32 * wts[z]  (barycenter partials)
   EPI 2: prox in-place: C[r][c] = f2b( exp(-(rv[z*N+c]+cv[r]-2*acc)*INVB) * b2f(C[r][c]) )
   EPI 3: atomicAdd(dout, sum (rv[c]+cv[r]-2*acc) * b2f(C[r][c]))            */
template<int EPI>
__global__ __launch_bounds__(256, 2)
void bgemm_k(const bfu* __restrict__ A, const bfu* __restrict__ B,
             void* __restrict__ Cp, size_t sA, size_t sB, size_t sC,
             const float* __restrict__ rv, const float* __restrict__ cv,
             const float* __restrict__ wts, float* __restrict__ dout) {
    __shared__ bfu As[128 * 32];
    __shared__ bfu Bs[128 * 32];
    __shared__ float wred[4];

    const int z  = blockIdx.z;
    const int bm = blockIdx.x * 128, bn = blockIdx.y * 128;
    const int tid = threadIdx.x;
    const int lane = tid & 63, wv = tid >> 6;
    const int wr = wv >> 1, wc = wv & 1;

    const bfu* Az = A + (size_t)z * sA;
    const bfu* Bz = B + (size_t)z * sB;

    const int sr = tid >> 2;          // staging row (0..63 per half)
    const int sk = (tid & 3) * 8;     // staging k-offset (elems)
    const int fr = lane & 15;         // fragment row/col
    const int ks = (lane >> 4) * 8;   // fragment k-slice

    f32x4 acc[4][4];
    #pragma unroll
    for (int i = 0; i < 4; i++)
        #pragma unroll
        for (int j = 0; j < 4; j++) acc[i][j] = (f32x4)0.f;

    for (int k0 = 0; k0 < N_; k0 += 32) {
        __syncthreads();   // prior frag reads done before restage
        #pragma unroll
        for (int h = 0; h < 2; ++h) {
            const int row = sr + h * 64;
            const bfu* ga = Az + (size_t)(bm + row) * N_ + k0 + sk;
            const bfu* gb = Bz + (size_t)(bn + row) * N_ + k0 + sk;
            __builtin_amdgcn_global_load_lds(
                (const __attribute__((address_space(1))) unsigned int*)ga,
                (__attribute__((address_space(3))) unsigned int*)&As[row * 32 + sk],
                16, 0, 0);
            __builtin_amdgcn_global_load_lds(
                (const __attribute__((address_space(1))) unsigned int*)gb,
                (__attribute__((address_space(3))) unsigned int*)&Bs[row * 32 + sk],
                16, 0, 0);
        }
        __syncthreads();   // drains vmcnt: staged data visible

        short8 af[4], bf[4];
        #pragma unroll
        for (int mi = 0; mi < 4; ++mi)
            af[mi] = *(const short8*)&As[(wr * 64 + mi * 16 + fr) * 32 + ks];
        #pragma unroll
        for (int ni = 0; ni < 4; ++ni)
            bf[ni] = *(const short8*)&Bs[(wc * 64 + ni * 16 + fr) * 32 + ks];
        #pragma unroll
        for (int mi = 0; mi < 4; ++mi)
            #pragma unroll
            for (int ni = 0; ni < 4; ++ni)
                acc[mi][ni] = __builtin_amdgcn_mfma_f32_16x16x32_bf16(
                    af[mi], bf[ni], acc[mi][ni], 0, 0, 0);
    }

    const int r0 = bm + wr * 64, c0 = bn + wc * 64;
    const int rq = (lane >> 4) * 4;   // C/D: col=lane&15, row=(lane>>4)*4+q

    if (EPI == 3) {
        const bfu* Tz = (const bfu*)Cp;
        float s = 0.f;
        #pragma unroll
        for (int mi = 0; mi < 4; ++mi)
            #pragma unroll
            for (int ni = 0; ni < 4; ++ni)
                #pragma unroll
                for (int q = 0; q < 4; ++q) {
                    const int row = r0 + mi * 16 + rq + q;
                    const int col = c0 + ni * 16 + fr;
                    s += (rv[col] + cv[row] - 2.f * acc[mi][ni][q]) *
                         b2f(Tz[(size_t)row * N_ + col]);
                }
        #pragma unroll
        for (int off = 32; off; off >>= 1) s += __shfl_down(s, off);
        if (lane == 0) wred[wv] = s;
        __syncthreads();
        if (tid == 0) atomicAdd(dout, wred[0] + wred[1] + wred[2] + wred[3]);
        return;
    }

    if (EPI == 1) {
        float* Cz = (float*)Cp + (size_t)z * sC;
        const float w = wts[z];
        #pragma unroll
        for (int mi = 0; mi < 4; ++mi)
            #pragma unroll
            for (int ni = 0; ni < 4; ++ni)
                #pragma unroll
                for (int q = 0; q < 4; ++q) {
                    const int row = r0 + mi * 16 + rq + q;
                    const int col = c0 + ni * 16 + fr;
                    Cz[(size_t)row * N_ + col] = w * acc[mi][ni][q];
                }
    } else if (EPI == 0) {
        bfu* Cz = (bfu*)Cp + (size_t)z * sC;
        #pragma unroll
        for (int mi = 0; mi < 4; ++mi)
            #pragma unroll
            for (int ni = 0; ni < 4; ++ni)
                #pragma unroll
                for (int q = 0; q < 4; ++q) {
                    const int row = r0 + mi * 16 + rq + q;
                    const int col = c0 + ni * 16 + fr;
                    Cz[(size_t)row * N_ + col] = f2b(acc[mi][ni][q]);
                }
    } else {  // EPI == 2: prox, in place on Tt
        bfu* Cz = (bfu*)Cp + (size_t)z * sC;
        const float* rvz = rv + z * N_;
        #pragma unroll
        for (int mi = 0; mi < 4; ++mi)
            #pragma unroll
            for (int ni = 0; ni < 4; ++ni)
                #pragma unroll
                for (int q = 0; q < 4; ++q) {
                    const int row = r0 + mi * 16 + rq + q;
                    const int col = c0 + ni * 16 + fr;
                    const float cost = rvz[col] + cv[row] - 2.f * acc[mi][ni][q];
                    const float t = b2f(Cz[(size_t)row * N_ + col]);
                    Cz[(size_t)row * N_ + col] = f2b(expf(-cost * INVB) * t);
                }
    }
}

/* ============ elementwise / reduction kernels ============ */

__global__ void sig2bf_k(const float* __restrict__ x, bfu* __restrict__ y, size_t n4) {
    size_t i = blockIdx.x * (size_t)blockDim.x + threadIdx.x;
    size_t st = (size_t)gridDim.x * blockDim.x;
    for (; i < n4; i += st) {
        float4 v = ((const float4*)x)[i];
        bfu o[4];
        o[0] = f2b(1.f / (1.f + expf(-v.x)));
        o[1] = f2b(1.f / (1.f + expf(-v.y)));
        o[2] = f2b(1.f / (1.f + expf(-v.z)));
        o[3] = f2b(1.f / (1.f + expf(-v.w)));
        *(ulong1*)&y[i * 4] = *(ulong1*)o;
    }
}

__global__ void cvt_bf_k(const float* __restrict__ x, bfu* __restrict__ y, size_t n4) {
    size_t i = blockIdx.x * (size_t)blockDim.x + threadIdx.x;
    size_t st = (size_t)gridDim.x * blockDim.x;
    for (; i < n4; i += st) {
        float4 v = ((const float4*)x)[i];
        bfu o[4];
        o[0] = f2b(v.x); o[1] = f2b(v.y); o[2] = f2b(v.z); o[3] = f2b(v.w);
        *(ulong1*)&y[i * 4] = *(ulong1*)o;
    }
}

// Tt[z][j][i] = ps[z*pstr + i] * pb[j]
__global__ void initTt_k(bfu* __restrict__ Tt, const float* __restrict__ ps, int pstr,
                         const float* __restrict__ pb, int nb) {
    size_t total8 = (size_t)nb * NN / 8;
    size_t st = (size_t)gridDim.x * blockDim.x;
    for (size_t i8 = blockIdx.x * (size_t)blockDim.x + threadIdx.x; i8 < total8; i8 += st) {
        size_t idx = i8 * 8;
        int z = (int)(idx >> 20);
        int j = (int)((idx >> 10) & (N_ - 1));
        int i0 = (int)(idx & (N_ - 1));
        float pbj = pb[j];
        const float* pz = ps + z * pstr;
        bfu o[8];
        #pragma unroll
        for (int t = 0; t < 8; ++t) o[t] = f2b(pz[i0 + t] * pbj);
        *(short8*)&Tt[idx] = *(short8*)o;
    }
}

// Tt[z][j][i] *= av[z*N+i] * bv[z*N+j]
__global__ void tupd_k(bfu* __restrict__ Tt, const float* __restrict__ av,
                       const float* __restrict__ bv, int nb) {
    size_t total8 = (size_t)nb * NN / 8;
    size_t st = (size_t)gridDim.x * blockDim.x;
    for (size_t i8 = blockIdx.x * (size_t)blockDim.x + threadIdx.x; i8 < total8; i8 += st) {
        size_t idx = i8 * 8;
        int z = (int)(idx >> 20);
        int j = (int)((idx >> 10) & (N_ - 1));
        int i0 = (int)(idx & (N_ - 1));
        float bj = bv[z * N_ + j];
        const float* az = av + z * N_;
        bfu t[8];
        *(short8*)t = *(const short8*)&Tt[idx];
        #pragma unroll
        for (int q = 0; q < 8; ++q) t[q] = f2b(b2f(t[q]) * az[i0 + q] * bj);
        *(short8*)&Tt[idx] = *(short8*)t;
    }
}

__global__ void copy_k(float* __restrict__ dst, const float* __restrict__ src, size_t n) {
    size_t i = blockIdx.x * (size_t)blockDim.x + threadIdx.x;
    size_t st = (size_t)gridDim.x * blockDim.x;
    for (; i < n; i += st) dst[i] = src[i];
}

__global__ void zero_k(float* p) {
    if (threadIdx.x == 0 && blockIdx.x == 0) p[0] = 0.f;
}

// bv[z*N+j] = pb[j] / (dot(Tt[z][j][:], av[z][:]) + eps)   — wave per row
__global__ void sinkb_k(const bfu* __restrict__ Tt, const float* __restrict__ av,
                        const float* __restrict__ pb, float* __restrict__ bv) {
    int z = blockIdx.y;
    int wv = threadIdx.x >> 6, lane = threadIdx.x & 63;
    int j = blockIdx.x * 4 + wv;
    const bfu* Tr = Tt + (size_t)z * NN + (size_t)j * N_;
    const float* az = av + z * N_;
    float s = 0.f;
    for (int c = lane * 8; c < N_; c += 512) {
        bfu t[8];
        *(short8*)t = *(const short8*)&Tr[c];
        #pragma unroll
        for (int q = 0; q < 8; ++q) s += b2f(t[q]) * az[c + q];
    }
    #pragma unroll
    for (int off = 32; off; off >>= 1) s += __shfl_down(s, off);
    if (lane == 0) bv[z * N_ + j] = pb[j] / (s + EPSV);
}

// av[z*N+i] = ps[z*pstr+i] / (sum_j Tt[z][j][i]*bv[z*N+j] + eps)  — 64 cols x 4 rowgroups
__global__ void sinka_k(const bfu* __restrict__ Tt, const float* __restrict__ bv,
                        const float* __restrict__ ps, int pstr, float* __restrict__ av) {
    int z = blockIdx.y;
    int rg = threadIdx.x >> 6, li = threadIdx.x & 63;
    int i = blockIdx.x * 64 + li;
    const bfu* Tz = Tt + (size_t)z * NN;
    const float* bz = bv + z * N_;
    float s = 0.f;
    for (int j = rg * 256; j < rg * 256 + 256; ++j)
        s += b2f(Tz[(size_t)j * N_ + i]) * bz[j];
    __shared__ float red[4][64];
    red[rg][li] = s;
    __syncthreads();
    if (rg == 0) {
        s = red[0][li] + red[1][li] + red[2][li] + red[3][li];
        av[z * N_ + i] = ps[z * pstr + i] / (s + EPSV);
    }
}

// y[z*N+r] = sum_c sigmoid(atoms[z][r][c])^2 * probs[z*N+c]   — wave per row
__global__ void sqsig_mv_k(const float* __restrict__ atoms, const float* __restrict__ probs,
                           float* __restrict__ y) {
    int z = blockIdx.y;
    int wv = threadIdx.x >> 6, lane = threadIdx.x & 63;
    int r = blockIdx.x * 4 + wv;
    const float* Ar = atoms + (size_t)z * NN + (size_t)r * N_;
    const float* pz = probs + z * N_;
    float s = 0.f;
    for (int c = lane * 4; c < N_; c += 256) {
        float4 v = *(const float4*)(Ar + c);
        float4 p = *(const float4*)(pz + c);
        float sx = 1.f / (1.f + expf(-v.x)), sy = 1.f / (1.f + expf(-v.y));
        float sz = 1.f / (1.f + expf(-v.z)), sw = 1.f / (1.f + expf(-v.w));
        s += sx * sx * p.x + sy * sy * p.y + sz * sz * p.z + sw * sw * p.w;
    }
    #pragma unroll
    for (int off = 32; off; off >>= 1) s += __shfl_down(s, off);
    if (lane == 0) y[z * N_ + r] = s;
}

// y[r] = sum_c A[r][c]^2 * p[c]   (fp32, single matrix) — wave per row
__global__ void sq_mv_k(const float* __restrict__ A, const float* __restrict__ p,
                        float* __restrict__ y) {
    int wv = threadIdx.x >> 6, lane = threadIdx.x & 63;
    int r = blockIdx.x * 4 + wv;
    const float* Ar = A + (size_t)r * N_;
    float s = 0.f;
    for (int c = lane * 4; c < N_; c += 256) {
        float4 v = *(const float4*)(Ar + c);
        float4 pv = *(const float4*)(p + c);
        s += v.x * v.x * pv.x + v.y * v.y * pv.y + v.z * v.z * pv.z + v.w * v.w * pv.w;
    }
    #pragma unroll
    for (int off = 32; off; off >>= 1) s += __shfl_down(s, off);
    if (lane == 0) y[r] = s;
}

// Gb[i][j] = (sum_z part[z][i][j]) / (pm[i]*pm[j]);  Gbt = bf16(Gb)
__global__ void reduce8_k(const float* __restrict__ part, const float* __restrict__ pm,
                          float* __restrict__ Gb, bfu* __restrict__ Gbt) {
    size_t total4 = NN / 4;
    size_t st = (size_t)gridDim.x * blockDim.x;
    for (size_t i4 = blockIdx.x * (size_t)blockDim.x + threadIdx.x; i4 < total4; i4 += st) {
        size_t idx = i4 * 4;
        int i = (int)(idx >> 10), j = (int)(idx & (N_ - 1));
        float pi = pm[i];
        float4 pj = *(const float4*)(pm + j);
        float4 s = *(const float4*)(part + idx);
        #pragma unroll
        for (int z = 1; z < K_; ++z) {
            float4 v = *(const float4*)(part + (size_t)z * NN + idx);
            s.x += v.x; s.y += v.y; s.z += v.z; s.w += v.w;
        }
        s.x /= pi * pj.x; s.y /= pi * pj.y; s.z /= pi * pj.z; s.w /= pi * pj.w;
        *(float4*)(Gb + idx) = s;
        bfu o[4];
        o[0] = f2b(s.x); o[1] = f2b(s.y); o[2] = f2b(s.z); o[3] = f2b(s.w);
        *(ulong1*)&Gbt[idx] = *(ulong1*)o;
    }
}

/* ============ host sequence ============ */

extern "C" void kernel_launch(void* const* d_in, const int* in_sizes, int n_in,
                              void* d_out, int out_size, void* d_ws, size_t ws_size,
                              hipStream_t stream) {
    const float* Gm    = (const float*)d_in[0];
    const float* pm    = (const float*)d_in[1];
    const float* atoms = (const float*)d_in[2];
    const float* probs = (const float*)d_in[3];
    const float* wts   = (const float*)d_in[4];
    float* out = (float*)d_out;                  // [0]=d_fgw, [1..]=G_bary (fp32)

    char* base = (char*)d_ws;
    bfu*   Gkt  = (bfu*)base;                    base += K_ * NN * 2;
    bfu*   Tt   = (bfu*)base;                    base += K_ * NN * 2;
    bfu*   M    = (bfu*)base;                    base += K_ * NN * 2;
    float* part = (float*)base;                  base += K_ * NN * 4;
    float* Gb   = (float*)base;                  base += NN * 4;
    bfu*   Gbt  = (bfu*)base;                    base += NN * 2;
    bfu*   Gmt  = (bfu*)base;                    base += NN * 2;
    float* Gk2ps = (float*)base;                 base += K_ * N_ * 4;
    float* Gm2pm = (float*)base;                 base += N_ * 4;
    float* Gb2pb = (float*)base;                 base += N_ * 4;
    float* avec  = (float*)base;                 base += K_ * N_ * 4;
    float* bvec  = (float*)base;                 base += K_ * N_ * 4;

    const dim3 blk(256);
    const dim3 g8(8, 8, K_);
    const dim3 g1(8, 8, 1);

    // setup
    sig2bf_k<<<2048, blk, 0, stream>>>(atoms, Gkt, K_ * NN / 4);
    sqsig_mv_k<<<dim3(N_ / 4, K_), blk, 0, stream>>>(atoms, probs, Gk2ps);
    sq_mv_k<<<dim3(N_ / 4, 1), blk, 0, stream>>>(Gm, pm, Gm2pm);
    cvt_bf_k<<<1024, blk, 0, stream>>>(Gm, Gmt, NN / 4);
    cvt_bf_k<<<1024, blk, 0, stream>>>(Gm, Gbt, NN / 4);
    hipMemcpyAsync(Gb, Gm, NN * sizeof(float), hipMemcpyDeviceToDevice, stream);

    for (int it = 0; it < GWBL; ++it) {
        sq_mv_k<<<dim3(N_ / 4, 1), blk, 0, stream>>>(Gb, pm, Gb2pb);
        initTt_k<<<2048, blk, 0, stream>>>(Tt, probs, N_, pm, K_);
        for (int ot = 0; ot < OTL; ++ot) {
            // M[i][n] = sum_k Gk[i][k] * Tt[n][k]          (= Gs @ T)
            bgemm_k<0><<<g8, blk, 0, stream>>>(Gkt, Tt, M, NN, NN, NN,
                nullptr, nullptr, nullptr, nullptr);
            // Tt[j][i] = exp(-(Gk2ps[i]+Gb2pb[j]-2*sum_n Gb[j][n]M[i][n])*10) * Tt[j][i]
            bgemm_k<2><<<g8, blk, 0, stream>>>(Gbt, M, Tt, 0, NN, NN,
                Gk2ps, Gb2pb, nullptr, nullptr);
            hipMemcpyAsync(avec, probs, (size_t)K_ * N_ * sizeof(float),
                           hipMemcpyDeviceToDevice, stream);
            for (int s = 0; s < SKL; ++s) {
                sinkb_k<<<dim3(N_ / 4, K_), blk, 0, stream>>>(Tt, avec, pm, bvec);
                sinka_k<<<dim3(N_ / 64, K_), blk, 0, stream>>>(Tt, bvec, probs, N_, avec);
            }
            tupd_k<<<2048, blk, 0, stream>>>(Tt, avec, bvec, K_);
        }
        // GTt[j][i'] = sum_k Tt[j][k]*Gk[i'][k]           (= (Gk @ T)^T), reuse M
        bgemm_k<0><<<g8, blk, 0, stream>>>(Tt, Gkt, M, NN, NN, NN,
            nullptr, nullptr, nullptr, nullptr);
        // part[z][i][j] = w_z * sum_n Tt[z][i][n]*GTt[z][j][n]  (= w_z T^T G T)
        bgemm_k<1><<<g8, blk, 0, stream>>>(Tt, M, part, NN, NN, NN,
            nullptr, nullptr, wts, nullptr);
        reduce8_k<<<1024, blk, 0, stream>>>(part, pm, Gb, Gbt);
    }

    // final fgwd(Gm, pm, Gb, pm)
    sq_mv_k<<<dim3(N_ / 4, 1), blk, 0, stream>>>(Gb, pm, Gb2pb);
    initTt_k<<<2048, blk, 0, stream>>>(Tt, pm, 0, pm, 1);
    for (int ot = 0; ot < OTL; ++ot) {
        bgemm_k<0><<<g1, blk, 0, stream>>>(Gmt, Tt, M, 0, NN, NN,
            nullptr, nullptr, nullptr, nullptr);
        bgemm_k<2><<<g1, blk, 0, stream>>>(Gbt, M, Tt, 0, NN, NN,
            Gm2pm, Gb2pb, nullptr, nullptr);
        hipMemcpyAsync(avec, pm, N_ * sizeof(float), hipMemcpyDeviceToDevice, stream);
        for (int s = 0; s < SKL; ++s) {
            sinkb_k<<<dim3(N_ / 4, 1), blk, 0, stream>>>(Tt, avec, pm, bvec);
            sinka_k<<<dim3(N_ / 64, 1), blk, 0, stream>>>(Tt, bvec, pm, 0, avec);
        }
        tupd_k<<<2048, blk, 0, stream>>>(Tt, avec, bvec, 1);
    }
    // d = sum_ij (Gm2pm[i] + Gb2pb[j] - 2*(Gm T Gb^T)[i][j]) * T[i][j]
    bgemm_k<0><<<g1, blk, 0, stream>>>(Gmt, Tt, M, 0, NN, NN,
        nullptr, nullptr, nullptr, nullptr);
    zero_k<<<1, 1, 0, stream>>>(out);
    bgemm_k<3><<<g1, blk, 0, stream>>>(Gbt, M, Tt, 0, NN, 0,
        Gm2pm, Gb2pb, nullptr, out);
    copy_k<<<1024, blk, 0, stream>>>(out + 1, Gb, NN);
}